// Round 2
// baseline (1161.235 us; speedup 1.0000x reference)
//
#include <hip/hip_runtime.h>

typedef unsigned short u16;
typedef unsigned int   u32;
typedef u16   u16x4 __attribute__((ext_vector_type(4)));
typedef u16   u16x8 __attribute__((ext_vector_type(8)));
typedef float f32x4 __attribute__((ext_vector_type(4)));
typedef __bf16 bf16x8 __attribute__((ext_vector_type(8)));

#define DEVI static __device__ __forceinline__

DEVI float b2f(u16 v) { u32 u = ((u32)v) << 16; return __builtin_bit_cast(float, u); }
DEVI u16 f2b(float f) {
  u32 u = __builtin_bit_cast(u32, f);
  u32 r = (u + 0x7FFFu + ((u >> 16) & 1u)) >> 16;
  return (u16)r;
}
DEVI f32x4 mfma16(u16x8 a, u16x8 b, f32x4 c) {
  return __builtin_amdgcn_mfma_f32_16x16x32_bf16(
      __builtin_bit_cast(bf16x8, a), __builtin_bit_cast(bf16x8, b), c, 0, 0, 0);
}

// problem constants
constexpr int C = 256, H = 384, W = 384, HW = H * W;   // 147456
constexpr int MROW = 64;       // tokens per block (4 windows of 16)
constexpr int AST  = 264;      // u16 stride of activation rows (528 B)
constexpr int VST  = 72;       // u16 stride of Vt rows (144 B)
// LDS offsets (u16 units)
constexpr int A_OFF  = 0;                       // act / AO region (64 x 264)
constexpr int Q_OFF  = MROW * AST;              // Q; later f32 OUT region
constexpr int K_OFF  = 2 * MROW * AST;          // K
constexpr int VT_OFF = 3 * MROW * AST;          // Vt: 256 x 72
constexpr int P_OFF  = VT_OFF + 256 * VST;      // P: 8 waves x 4 wins x 256
constexpr int SMEM_U16 = P_OFF + 8 * 4 * 256;   // 77312 u16 = 154624 B
constexpr int OST = 257;                        // f32 stride of OUT region (floats)
// workspace offsets (u16 units): transposed bf16 weights  W^T[n][k]
constexpr int WQT = 0, WKVT = 65536, WOT = 196608;    // total 262144 u16 = 512 KB

__global__ __launch_bounds__(256) void prep_transpose(
    const float* __restrict__ wq, const float* __restrict__ wkv,
    const float* __restrict__ wo, u16* __restrict__ wsp) {
  __shared__ u16 tl[64][65];
  int bid = blockIdx.x, tid = threadIdx.x;
  const float* in; u16* out; int N, kt, nt;
  if (bid < 16)      { in = wq;  out = wsp + WQT;  N = 256; int t = bid;      kt = t >> 2; nt = t & 3; }
  else if (bid < 48) { in = wkv; out = wsp + WKVT; N = 512; int t = bid - 16; kt = t >> 3; nt = t & 7; }
  else               { in = wo;  out = wsp + WOT;  N = 256; int t = bid - 48; kt = t >> 2; nt = t & 3; }
#pragma unroll
  for (int i = 0; i < 16; ++i) {
    int fl = i * 256 + tid;
    int r = fl >> 6, c = fl & 63;
    tl[r][c] = f2b(in[(kt * 64 + r) * N + nt * 64 + c]);
  }
  __syncthreads();
#pragma unroll
  for (int i = 0; i < 16; ++i) {
    int fl = i * 256 + tid;
    int r = fl >> 6, c = fl & 63;
    out[(nt * 64 + r) * 256 + kt * 64 + c] = tl[c][r];
  }
}

__global__ __launch_bounds__(512, 2) void xattn_main(
    const float* __restrict__ x, const float* __restrict__ cond,
    const float* __restrict__ n1w, const float* __restrict__ n2w,
    const float* __restrict__ bq, const float* __restrict__ bkv, const float* __restrict__ bo,
    const float* __restrict__ btab, const u16* __restrict__ wsp, float* __restrict__ out) {
  __shared__ __align__(16) u16 smem[SMEM_U16];
  __shared__ float biasb[256];
  __shared__ float nwb[256];

  const int tid  = threadIdx.x;
  const int lane = tid & 63, wv = tid >> 6;
  const int l15  = lane & 15, quad = lane >> 4;

  // block -> (batch, window-row, w-group of 4 windows)
  int bid = blockIdx.x;
  const int b  = bid / 2304; int rem = bid % 2304;
  const int h0 = (rem / 24) * 4;
  const int w0 = (rem % 24) * 16;
  const long gbase = (long)b * ((long)C * HW);

  // relative-position bias 16x16 into LDS; norm2 weights (x is normalized first)
  if (tid < 256) {
    int row = tid >> 4, col = tid & 15;
    int idx = ((row >> 2) - (col >> 2) + 3) * 7 + ((row & 3) - (col & 3) + 3);
    biasb[tid] = btab[idx];
    nwb[tid]   = n2w[tid];
  }

  // ---------- stage a 64-token x 256-ch tile into A region (f32 -> bf16) ----
  auto stage = [&](const float* __restrict__ src, f32x4* save) {
#pragma unroll
    for (int it = 0; it < 8; ++it) {
      int q = it * 512 + tid;
      int ch = q >> 4, dy = (q >> 2) & 3, win = q & 3;
      const float* gp = src + gbase + (long)ch * HW + (long)(h0 + dy) * W + (w0 + win * 4);
      f32x4 v = *(const f32x4*)gp;
      if (save) save[it] = v;
      int base = A_OFF + (win * 16 + dy * 4) * AST + ch;
#pragma unroll
      for (int j = 0; j < 4; ++j) {
        int jj = (j + win) & 3;                 // stagger to spread LDS banks
        smem[base + jj * AST] = f2b(v[jj]);
      }
    }
  };

  // ---------- in-place LayerNorm on A region (8 threads per token) ----------
  auto layernorm = [&]() {
    int tk = tid >> 3, part = tid & 7;
    int base = A_OFF + tk * AST + part * 32;
    float vals[32];
    float s = 0.f, s2 = 0.f;
#pragma unroll
    for (int cg = 0; cg < 4; ++cg) {
      u16x8 v = *(const u16x8*)&smem[base + cg * 8];
#pragma unroll
      for (int j = 0; j < 8; ++j) { float f = b2f(v[j]); vals[cg * 8 + j] = f; s += f; s2 += f * f; }
    }
    s  += __shfl_xor(s, 1, 8);  s  += __shfl_xor(s, 2, 8);  s  += __shfl_xor(s, 4, 8);
    s2 += __shfl_xor(s2, 1, 8); s2 += __shfl_xor(s2, 2, 8); s2 += __shfl_xor(s2, 4, 8);
    float mean = s * (1.f / 256.f);
    float var  = s2 * (1.f / 256.f) - mean * mean;
    float rs   = rsqrtf(var + 1e-5f);
#pragma unroll
    for (int cg = 0; cg < 4; ++cg) {
      u16x8 o;
#pragma unroll
      for (int j = 0; j < 8; ++j) {
        int ch = part * 32 + cg * 8 + j;
        o[j] = f2b((vals[cg * 8 + j] - mean) * rs * nwb[ch]);
      }
      *(u16x8*)&smem[base + cg * 8] = o;
    }
  };

  f32x4 xs[8];                       // raw f32 x tile kept for exact residual
  stage(x, xs);
  __syncthreads();
  layernorm();                       // kv_in = LN(x, norm2_w)
  __syncthreads();

  // ---------- KV-GEMM: (64x256)@(256x512); wave wv covers n = 64*wv .. +63 ---
  {
    f32x4 acc[4][4];
#pragma unroll
    for (int m = 0; m < 4; ++m)
#pragma unroll
      for (int j = 0; j < 4; ++j) acc[m][j] = f32x4{0.f, 0.f, 0.f, 0.f};
    const u16* bt[4];
#pragma unroll
    for (int j = 0; j < 4; ++j) {
      int n = wv * 64 + j * 16 + l15;
      bt[j] = wsp + WKVT + n * 256 + quad * 8;
    }
    u16x8 bcur[4], bnext[4];
#pragma unroll
    for (int j = 0; j < 4; ++j) bcur[j] = *(const u16x8*)bt[j];
#pragma unroll
    for (int kk = 0; kk < 8; ++kk) {
      if (kk < 7) {
#pragma unroll
        for (int j = 0; j < 4; ++j) bnext[j] = *(const u16x8*)(bt[j] + (kk + 1) * 32);
      }
      u16x8 af[4];
#pragma unroll
      for (int mt = 0; mt < 4; ++mt)
        af[mt] = *(const u16x8*)&smem[A_OFF + (mt * 16 + l15) * AST + kk * 32 + quad * 8];
#pragma unroll
      for (int mt = 0; mt < 4; ++mt)
#pragma unroll
        for (int j = 0; j < 4; ++j) acc[mt][j] = mfma16(af[mt], bcur[j], acc[mt][j]);
      if (kk < 7) {
#pragma unroll
        for (int j = 0; j < 4; ++j) bcur[j] = bnext[j];
      }
    }
    // epilogue: waves 0-3 -> K [tok][ch], waves 4-7 -> Vt [d][tok]
#pragma unroll
    for (int j = 0; j < 4; ++j) {
      int n = wv * 64 + j * 16 + l15;
      float bb = bkv[n];
#pragma unroll
      for (int mt = 0; mt < 4; ++mt)
#pragma unroll
        for (int r = 0; r < 4; ++r) {
          int row = mt * 16 + quad * 4 + r;
          u16 val = f2b(acc[mt][j][r] + bb);
          if (wv < 4) smem[K_OFF + row * AST + n] = val;
          else        smem[VT_OFF + (n - 256) * VST + row] = val;
        }
    }
  }
  __syncthreads();

  // ---------- stage cond, LN with norm1_w ----------
  if (tid < 256) nwb[tid] = n1w[tid];
  stage(cond, nullptr);
  __syncthreads();
  layernorm();                       // q_in = LN(cond, norm1_w)
  __syncthreads();

  // ---------- Q-GEMM: (64x256)@(256x256), scale 1/sqrt(32) folded in ---------
  {
    f32x4 acc[4][2];
#pragma unroll
    for (int m = 0; m < 4; ++m) { acc[m][0] = f32x4{0.f,0.f,0.f,0.f}; acc[m][1] = f32x4{0.f,0.f,0.f,0.f}; }
    const u16* bt[2];
#pragma unroll
    for (int j = 0; j < 2; ++j) {
      int n = wv * 32 + j * 16 + l15;
      bt[j] = wsp + WQT + n * 256 + quad * 8;
    }
    u16x8 bcur[2], bnext[2];
#pragma unroll
    for (int j = 0; j < 2; ++j) bcur[j] = *(const u16x8*)bt[j];
#pragma unroll
    for (int kk = 0; kk < 8; ++kk) {
      if (kk < 7) {
#pragma unroll
        for (int j = 0; j < 2; ++j) bnext[j] = *(const u16x8*)(bt[j] + (kk + 1) * 32);
      }
      u16x8 af[4];
#pragma unroll
      for (int mt = 0; mt < 4; ++mt)
        af[mt] = *(const u16x8*)&smem[A_OFF + (mt * 16 + l15) * AST + kk * 32 + quad * 8];
#pragma unroll
      for (int mt = 0; mt < 4; ++mt)
#pragma unroll
        for (int j = 0; j < 2; ++j) acc[mt][j] = mfma16(af[mt], bcur[j], acc[mt][j]);
      if (kk < 7) {
#pragma unroll
        for (int j = 0; j < 2; ++j) bcur[j] = bnext[j];
      }
    }
    const float qs = 0.17677669529663687f;  // 1/sqrt(32)
#pragma unroll
    for (int j = 0; j < 2; ++j) {
      int n = wv * 32 + j * 16 + l15;
      float bb = bq[n];
#pragma unroll
      for (int mt = 0; mt < 4; ++mt)
#pragma unroll
        for (int r = 0; r < 4; ++r) {
          int row = mt * 16 + quad * 4 + r;
          smem[Q_OFF + row * AST + n] = f2b((acc[mt][j][r] + bb) * qs);
        }
    }
  }
  __syncthreads();

  // ---------- attention scores + softmax: wave wv owns head wv, 4 windows ----
  {
    const int hb = wv * 32;
#pragma unroll
    for (int win = 0; win < 4; ++win) {
      u16x8 aq = *(const u16x8*)&smem[Q_OFF + (win * 16 + l15) * AST + hb + quad * 8];
      u16x8 bk = *(const u16x8*)&smem[K_OFF + (win * 16 + l15) * AST + hb + quad * 8];
      f32x4 sc = mfma16(aq, bk, f32x4{0.f, 0.f, 0.f, 0.f});
      int pb = P_OFF + (wv * 4 + win) * 256;
#pragma unroll
      for (int r = 0; r < 4; ++r) {
        float s = sc[r] + biasb[(quad * 4 + r) * 16 + l15];
        float mx = s;
        mx = fmaxf(mx, __shfl_xor(mx, 1, 16)); mx = fmaxf(mx, __shfl_xor(mx, 2, 16));
        mx = fmaxf(mx, __shfl_xor(mx, 4, 16)); mx = fmaxf(mx, __shfl_xor(mx, 8, 16));
        float e = __expf(s - mx);
        float sm = e;
        sm += __shfl_xor(sm, 1, 16); sm += __shfl_xor(sm, 2, 16);
        sm += __shfl_xor(sm, 4, 16); sm += __shfl_xor(sm, 8, 16);
        smem[pb + (quad * 4 + r) * 16 + l15] = f2b(e / sm);
      }
    }
  }
  __syncthreads();
  {
    const int hb = wv * 32;
    f32x4 accO[4][2];
#pragma unroll
    for (int w2 = 0; w2 < 4; ++w2) { accO[w2][0] = f32x4{0.f,0.f,0.f,0.f}; accO[w2][1] = f32x4{0.f,0.f,0.f,0.f}; }
#pragma unroll
    for (int win = 0; win < 4; ++win) {
      int pb = P_OFF + (wv * 4 + win) * 256;
      u16x8 ap = *(const u16x8*)&smem[pb + l15 * 16 + (quad & 1) * 8];
      if (quad >= 2) ap = u16x8{0, 0, 0, 0, 0, 0, 0, 0};   // zero-pad k=16..31
#pragma unroll
      for (int ntp = 0; ntp < 2; ++ntp) {
        u16x8 bv = *(const u16x8*)&smem[VT_OFF + (hb + ntp * 16 + l15) * VST + win * 16 + (quad & 1) * 8];
        accO[win][ntp] = mfma16(ap, bv, accO[win][ntp]);
      }
    }
    // write attn-out into A region (A is dead now)
#pragma unroll
    for (int win = 0; win < 4; ++win)
#pragma unroll
      for (int ntp = 0; ntp < 2; ++ntp)
#pragma unroll
        for (int r = 0; r < 4; ++r) {
          int row = win * 16 + quad * 4 + r;
          int col = hb + ntp * 16 + l15;
          smem[A_OFF + row * AST + col] = f2b(accO[win][ntp][r]);
        }
  }
  __syncthreads();

  // ---------- out-proj: (64x256)@(256x256) -> f32 OUT region ----------
  float* fO = (float*)(void*)&smem[Q_OFF];   // 64 x 257 floats, over dead Q/K/Vt/P
  {
    f32x4 acc[4][2];
#pragma unroll
    for (int m = 0; m < 4; ++m) { acc[m][0] = f32x4{0.f,0.f,0.f,0.f}; acc[m][1] = f32x4{0.f,0.f,0.f,0.f}; }
    const u16* bt[2];
#pragma unroll
    for (int j = 0; j < 2; ++j) {
      int n = wv * 32 + j * 16 + l15;
      bt[j] = wsp + WOT + n * 256 + quad * 8;
    }
    u16x8 bcur[2], bnext[2];
#pragma unroll
    for (int j = 0; j < 2; ++j) bcur[j] = *(const u16x8*)bt[j];
#pragma unroll
    for (int kk = 0; kk < 8; ++kk) {
      if (kk < 7) {
#pragma unroll
        for (int j = 0; j < 2; ++j) bnext[j] = *(const u16x8*)(bt[j] + (kk + 1) * 32);
      }
      u16x8 af[4];
#pragma unroll
      for (int mt = 0; mt < 4; ++mt)
        af[mt] = *(const u16x8*)&smem[A_OFF + (mt * 16 + l15) * AST + kk * 32 + quad * 8];
#pragma unroll
      for (int mt = 0; mt < 4; ++mt)
#pragma unroll
        for (int j = 0; j < 2; ++j) acc[mt][j] = mfma16(af[mt], bcur[j], acc[mt][j]);
      if (kk < 7) {
#pragma unroll
        for (int j = 0; j < 2; ++j) bcur[j] = bnext[j];
      }
    }
#pragma unroll
    for (int j = 0; j < 2; ++j) {
      int n = wv * 32 + j * 16 + l15;
      float bb = bo[n];
#pragma unroll
      for (int mt = 0; mt < 4; ++mt)
#pragma unroll
        for (int r = 0; r < 4; ++r) {
          int row = mt * 16 + quad * 4 + r;
          fO[row * OST + n] = acc[mt][j][r] + bb;
        }
    }
  }
  __syncthreads();

  // ---------- epilogue: exact f32 residual + coalesced float4 store ----------
#pragma unroll
  for (int it = 0; it < 8; ++it) {
    int q = it * 512 + tid;
    int ch = q >> 4, dy = (q >> 2) & 3, win = q & 3;
    int tok0 = win * 16 + dy * 4;
    f32x4 o;
#pragma unroll
    for (int j = 0; j < 4; ++j)
      o[j] = fO[(tok0 + j) * OST + ch] + xs[it][j];
    float* gp = out + gbase + (long)ch * HW + (long)(h0 + dy) * W + (w0 + win * 4);
    *(f32x4*)gp = o;
  }
}

extern "C" void kernel_launch(void* const* d_in, const int* in_sizes, int n_in,
                              void* d_out, int out_size, void* d_ws, size_t ws_size,
                              hipStream_t stream) {
  const float* x    = (const float*)d_in[0];
  const float* cond = (const float*)d_in[1];
  const float* n1w  = (const float*)d_in[2];
  const float* n2w  = (const float*)d_in[3];
  const float* wq   = (const float*)d_in[4];
  const float* bq   = (const float*)d_in[5];
  const float* wkv  = (const float*)d_in[6];
  const float* bkv  = (const float*)d_in[7];
  const float* wo   = (const float*)d_in[8];
  const float* bo   = (const float*)d_in[9];
  const float* btab = (const float*)d_in[10];
  u16* wsp = (u16*)d_ws;     // 512 KB of transposed bf16 weights
  float* outp = (float*)d_out;

  prep_transpose<<<64, 256, 0, stream>>>(wq, wkv, wo, wsp);
  xattn_main<<<4608, 512, 0, stream>>>(x, cond, n1w, n2w, bq, bkv, bo, btab, wsp, outp);
}